// Round 7
// baseline (394.538 us; speedup 1.0000x reference)
//
#include <hip/hip_runtime.h>
#include <hip/hip_cooperative_groups.h>

namespace cg = cooperative_groups;

#define N_NODES 50000
#define NEDGE 800000
#define NB 256
#define NT 512
#define NTHREADS (NB * NT)    // 131072
#define NTILES 782            // ceil(50000/64)
#define NSCAN 98              // ceil(50000/512)

// ws layout:
//   fb     [N_NODES*64]  ushort (bf16 features)  6.4 MB
//   cnt    [N_NODES]     int
//   offs   [N_NODES+1]   int
//   cursor [N_NODES]     int
//   bsum   [NSCAN]       int
//   scol   [NEDGE]       int

__device__ __forceinline__ unsigned short f2bf(float x) {
    unsigned int u = __float_as_uint(x);
    unsigned int r = (u + 0x7FFFu + ((u >> 16) & 1u)) >> 16;  // RNE
    return (unsigned short)r;
}

__device__ __forceinline__ void acc8(float* a, uint4 v) {
    a[0] += __uint_as_float(v.x << 16);
    a[1] += __uint_as_float(v.x & 0xffff0000u);
    a[2] += __uint_as_float(v.y << 16);
    a[3] += __uint_as_float(v.y & 0xffff0000u);
    a[4] += __uint_as_float(v.z << 16);
    a[5] += __uint_as_float(v.z & 0xffff0000u);
    a[6] += __uint_as_float(v.w << 16);
    a[7] += __uint_as_float(v.w & 0xffff0000u);
}

// ---- Tile worker shared by both paths: gather + GEMM for 64 nodes ----
__device__ __forceinline__ void do_tile(
    int base, int t, float (*cbuf)[132],
    const float* __restrict__ feat, const unsigned short* __restrict__ fb,
    const int* __restrict__ offs, const int* __restrict__ scol,
    const float* __restrict__ W, float* __restrict__ out) {
    // Gather: 8 lanes per node (16 B bf16 chunks), 64 nodes per tile.
    {
        const int s = t >> 3;  // node slot 0..63
        const int g = t & 7;   // uint4 group within 128-byte bf16 row
        int node = base + s;
        int st = 0, en = 0;
        if (node < N_NODES) { st = offs[node]; en = offs[node + 1]; }
        float a[8] = {0.f, 0.f, 0.f, 0.f, 0.f, 0.f, 0.f, 0.f};
        int p = st;
        for (; p + 4 <= en; p += 4) {
            int c0 = scol[p], c1 = scol[p + 1], c2 = scol[p + 2], c3 = scol[p + 3];
            uint4 v0 = ((const uint4*)(fb + (size_t)c0 * 64))[g];
            uint4 v1 = ((const uint4*)(fb + (size_t)c1 * 64))[g];
            uint4 v2 = ((const uint4*)(fb + (size_t)c2 * 64))[g];
            uint4 v3 = ((const uint4*)(fb + (size_t)c3 * 64))[g];
            acc8(a, v0); acc8(a, v1); acc8(a, v2); acc8(a, v3);
        }
        for (; p < en; p++) {
            int c = scol[p];
            uint4 v = ((const uint4*)(fb + (size_t)c * 64))[g];
            acc8(a, v);
        }
        float rd = 1.0f / (float)(en - st + 1);
        *(float4*)&cbuf[s][64 + g * 8] =
            make_float4(a[0] * rd, a[1] * rd, a[2] * rd, a[3] * rd);
        *(float4*)&cbuf[s][64 + g * 8 + 4] =
            make_float4(a[4] * rd, a[5] * rd, a[6] * rd, a[7] * rd);
        float4 f0 = make_float4(0.f, 0.f, 0.f, 0.f);
        float4 f1 = make_float4(0.f, 0.f, 0.f, 0.f);
        if (node < N_NODES) {
            f0 = *(const float4*)&feat[node * 64 + g * 8];
            f1 = *(const float4*)&feat[node * 64 + g * 8 + 4];
        }
        *(float4*)&cbuf[s][g * 8] = f0;
        *(float4*)&cbuf[s][g * 8 + 4] = f1;
    }
    __syncthreads();

    // GEMM: thread computes 2 rows x 8 cols
    {
        const int g = t & 15;
        const int r0 = (t >> 4) * 2;

        float acc0[2][4];
        float acc1[2][4];
#pragma unroll
        for (int a = 0; a < 2; a++)
#pragma unroll
            for (int c = 0; c < 4; c++) { acc0[a][c] = 0.f; acc1[a][c] = 0.f; }

        for (int k = 0; k < 128; k += 4) {
            float4 cv[2];
#pragma unroll
            for (int a = 0; a < 2; a++) cv[a] = *(const float4*)&cbuf[r0 + a][k];
#pragma unroll
            for (int kk = 0; kk < 4; kk++) {
                float4 w0 = *(const float4*)&W[(k + kk) * 128 + g * 4];
                float4 w1 = *(const float4*)&W[(k + kk) * 128 + 64 + g * 4];
#pragma unroll
                for (int a = 0; a < 2; a++) {
                    float c = ((const float*)&cv[a])[kk];
                    acc0[a][0] += c * w0.x; acc0[a][1] += c * w0.y;
                    acc0[a][2] += c * w0.z; acc0[a][3] += c * w0.w;
                    acc1[a][0] += c * w1.x; acc1[a][1] += c * w1.y;
                    acc1[a][2] += c * w1.z; acc1[a][3] += c * w1.w;
                }
            }
        }

#pragma unroll
        for (int a = 0; a < 2; a++) {
            int gr = base + r0 + a;
            if (gr < N_NODES) {
                float4 o0 = make_float4(fmaxf(acc0[a][0], 0.f), fmaxf(acc0[a][1], 0.f),
                                        fmaxf(acc0[a][2], 0.f), fmaxf(acc0[a][3], 0.f));
                float4 o1 = make_float4(fmaxf(acc1[a][0], 0.f), fmaxf(acc1[a][1], 0.f),
                                        fmaxf(acc1[a][2], 0.f), fmaxf(acc1[a][3], 0.f));
                *(float4*)&out[gr * 128 + g * 4] = o0;
                *(float4*)&out[gr * 128 + 64 + g * 4] = o1;
            }
        }
    }
    __syncthreads();  // cbuf reused by next tile
}

// ================= Cooperative single-kernel path =================
__global__ __launch_bounds__(512, 2) void mega_kernel(
    const float* __restrict__ feat,
    const int* __restrict__ row,
    const int* __restrict__ col,
    const float* __restrict__ W,
    unsigned short* __restrict__ fb,
    int* __restrict__ cnt,
    int* __restrict__ offs,
    int* __restrict__ cursor,
    int* __restrict__ bsum,
    int* __restrict__ scol,
    float* __restrict__ out) {
    cg::grid_group grid = cg::this_grid();

    __shared__ float cbuf[64][132];  // 33.8 KB
    __shared__ int ibuf[512];
    __shared__ int wpart[8];
    __shared__ int s_bp;

    const int t = threadIdx.x;
    const int b = blockIdx.x;
    const int gid = b * NT + t;

    // ---- Phase A: zero cnt + convert feat -> bf16 ----
    for (int i = gid; i < N_NODES; i += NTHREADS) cnt[i] = 0;
    for (int i = gid; i < N_NODES * 16; i += NTHREADS) {
        float4 v = ((const float4*)feat)[i];
        ushort4 o;
        o.x = f2bf(v.x); o.y = f2bf(v.y); o.z = f2bf(v.z); o.w = f2bf(v.w);
        ((ushort4*)fb)[i] = o;
    }
    grid.sync();

    // ---- Phase B: histogram (int4 per iteration) ----
    for (int i = gid; i < NEDGE / 4; i += NTHREADS) {
        int4 r = ((const int4*)row)[i];
        atomicAdd(&cnt[r.x], 1);
        atomicAdd(&cnt[r.y], 1);
        atomicAdd(&cnt[r.z], 1);
        atomicAdd(&cnt[r.w], 1);
    }
    grid.sync();

    // ---- Phase C1: per-chunk sums (blocks 0..NSCAN-1) ----
    if (b < NSCAN) {
        int i = b * 512 + t;
        int s = (i < N_NODES) ? cnt[i] : 0;
#pragma unroll
        for (int off = 32; off > 0; off >>= 1) s += __shfl_down(s, off, 64);
        if ((t & 63) == 0) wpart[t >> 6] = s;
        __syncthreads();
        if (t == 0) {
            int tot = 0;
#pragma unroll
            for (int w = 0; w < 8; w++) tot += wpart[w];
            bsum[b] = tot;
        }
    }
    grid.sync();

    // ---- Phase C2: scan -> offs, cursor ----
    if (b < NSCAN) {
        int i = b * 512 + t;
        int v = (i < N_NODES) ? cnt[i] : 0;
        ibuf[t] = v;
        __syncthreads();
        for (int off = 1; off < 512; off <<= 1) {
            int add = (t >= off) ? ibuf[t - off] : 0;
            __syncthreads();
            ibuf[t] += add;
            __syncthreads();
        }
        int excl = ibuf[t] - v;

        int p = (t < b) ? bsum[t] : 0;  // NSCAN=98 <= 512
#pragma unroll
        for (int off = 32; off > 0; off >>= 1) p += __shfl_down(p, off, 64);
        if ((t & 63) == 0) wpart[t >> 6] = p;
        __syncthreads();
        if (t == 0) {
            int tot = 0;
#pragma unroll
            for (int w = 0; w < 8; w++) tot += wpart[w];
            s_bp = tot;
        }
        __syncthreads();
        int o = s_bp + excl;
        if (i < N_NODES) { offs[i] = o; cursor[i] = o; }
        if (i == N_NODES - 1) offs[N_NODES] = o + v;
    }
    grid.sync();

    // ---- Phase D: reorder (CSR build) ----
    for (int i = gid; i < NEDGE / 4; i += NTHREADS) {
        int4 r = ((const int4*)row)[i];
        int4 c = ((const int4*)col)[i];
        scol[atomicAdd(&cursor[r.x], 1)] = c.x;
        scol[atomicAdd(&cursor[r.y], 1)] = c.y;
        scol[atomicAdd(&cursor[r.z], 1)] = c.z;
        scol[atomicAdd(&cursor[r.w], 1)] = c.w;
    }
    grid.sync();

    // ---- Phase E: gather + GEMM tiles, grid-stride ----
    for (int tile = b; tile < NTILES; tile += NB) {
        do_tile(tile * 64, t, cbuf, feat, fb, offs, scol, W, out);
    }
}

// ================= Fallback multi-kernel path =================
__global__ __launch_bounds__(256) void conv_zero_kernel(
    const float* __restrict__ feat, unsigned short* __restrict__ fb,
    int* __restrict__ cnt) {
    int i = blockIdx.x * 256 + threadIdx.x;
    if (i < N_NODES) cnt[i] = 0;
    if (i < N_NODES * 16) {
        float4 v = ((const float4*)feat)[i];
        ushort4 o;
        o.x = f2bf(v.x); o.y = f2bf(v.y); o.z = f2bf(v.z); o.w = f2bf(v.w);
        ((ushort4*)fb)[i] = o;
    }
}

__global__ __launch_bounds__(256) void hist_kernel(
    const int* __restrict__ row, int* __restrict__ cnt) {
    int i = blockIdx.x * 256 + threadIdx.x;
    if (i < NEDGE / 4) {
        int4 r = ((const int4*)row)[i];
        atomicAdd(&cnt[r.x], 1);
        atomicAdd(&cnt[r.y], 1);
        atomicAdd(&cnt[r.z], 1);
        atomicAdd(&cnt[r.w], 1);
    }
}

__global__ __launch_bounds__(512) void blocksum_kernel(
    const int* __restrict__ cnt, int* __restrict__ bsum) {
    __shared__ int wpart[8];
    int t = threadIdx.x;
    int i = blockIdx.x * 512 + t;
    int v = (i < N_NODES) ? cnt[i] : 0;
#pragma unroll
    for (int off = 32; off > 0; off >>= 1) v += __shfl_down(v, off, 64);
    if ((t & 63) == 0) wpart[t >> 6] = v;
    __syncthreads();
    if (t == 0) {
        int tot = 0;
#pragma unroll
        for (int w = 0; w < 8; w++) tot += wpart[w];
        bsum[blockIdx.x] = tot;
    }
}

__global__ __launch_bounds__(512) void scan_kernel(
    const int* __restrict__ cnt, const int* __restrict__ bsum,
    int* __restrict__ offs, int* __restrict__ cursor) {
    __shared__ int ibuf[512];
    __shared__ int wpart[8];
    __shared__ int s_bp;
    const int t = threadIdx.x;
    const int i = blockIdx.x * 512 + t;
    int v = (i < N_NODES) ? cnt[i] : 0;

    ibuf[t] = v;
    __syncthreads();
    for (int off = 1; off < 512; off <<= 1) {
        int add = (t >= off) ? ibuf[t - off] : 0;
        __syncthreads();
        ibuf[t] += add;
        __syncthreads();
    }
    int excl = ibuf[t] - v;

    int p = (t < (int)blockIdx.x) ? bsum[t] : 0;
#pragma unroll
    for (int off = 32; off > 0; off >>= 1) p += __shfl_down(p, off, 64);
    if ((t & 63) == 0) wpart[t >> 6] = p;
    __syncthreads();
    if (t == 0) {
        int tot = 0;
#pragma unroll
        for (int w = 0; w < 8; w++) tot += wpart[w];
        s_bp = tot;
    }
    __syncthreads();
    int o = s_bp + excl;
    if (i < N_NODES) { offs[i] = o; cursor[i] = o; }
    if (i == N_NODES - 1) offs[N_NODES] = o + v;
}

__global__ __launch_bounds__(256) void reorder_kernel(
    const int* __restrict__ row, const int* __restrict__ col,
    int* __restrict__ cursor, int* __restrict__ scol) {
    int i = blockIdx.x * 256 + threadIdx.x;
    if (i < NEDGE / 4) {
        int4 r = ((const int4*)row)[i];
        int4 c = ((const int4*)col)[i];
        scol[atomicAdd(&cursor[r.x], 1)] = c.x;
        scol[atomicAdd(&cursor[r.y], 1)] = c.y;
        scol[atomicAdd(&cursor[r.z], 1)] = c.z;
        scol[atomicAdd(&cursor[r.w], 1)] = c.w;
    }
}

__global__ __launch_bounds__(512) void fused_kernel(
    const float* __restrict__ feat,
    const unsigned short* __restrict__ fb,
    const int* __restrict__ offs,
    const int* __restrict__ scol,
    const float* __restrict__ W,
    float* __restrict__ out) {
    __shared__ float cbuf[64][132];
    do_tile(blockIdx.x * 64, threadIdx.x, cbuf, feat, fb, offs, scol, W, out);
}

extern "C" void kernel_launch(void* const* d_in, const int* in_sizes, int n_in,
                              void* d_out, int out_size, void* d_ws, size_t ws_size,
                              hipStream_t stream) {
    const float* feat = (const float*)d_in[0];
    const int* row = (const int*)d_in[1];
    const int* col = (const int*)d_in[2];
    const float* W = (const float*)d_in[3];
    float* out = (float*)d_out;

    unsigned short* fb = (unsigned short*)d_ws;  // 6.4 MB
    int* cnt = (int*)((char*)d_ws + (size_t)N_NODES * 64 * 2);
    int* offs = cnt + N_NODES;       // N_NODES+1
    int* cursor = offs + N_NODES + 1;
    int* bsum = cursor + N_NODES;    // NSCAN
    int* scol = bsum + NSCAN;

    void* args[] = {(void*)&feat, (void*)&row, (void*)&col, (void*)&W,
                    (void*)&fb, (void*)&cnt, (void*)&offs, (void*)&cursor,
                    (void*)&bsum, (void*)&scol, (void*)&out};
    hipError_t err = hipLaunchCooperativeKernel((void*)mega_kernel, dim3(NB),
                                                dim3(NT), args, 0, stream);
    if (err != hipSuccess) {
        // Fallback: proven multi-kernel chain (same math, same buffers)
        conv_zero_kernel<<<(N_NODES * 16 + 255) / 256, 256, 0, stream>>>(feat, fb, cnt);
        int e4blocks = (NEDGE / 4 + 255) / 256;
        hist_kernel<<<e4blocks, 256, 0, stream>>>(row, cnt);
        blocksum_kernel<<<NSCAN, 512, 0, stream>>>(cnt, bsum);
        scan_kernel<<<NSCAN, 512, 0, stream>>>(cnt, bsum, offs, cursor);
        reorder_kernel<<<e4blocks, 256, 0, stream>>>(row, col, cursor, scol);
        fused_kernel<<<NTILES, 512, 0, stream>>>(feat, fb, offs, scol, W, out);
    }
}

// Round 8
// 221.296 us; speedup vs baseline: 1.7829x; 1.7829x over previous
//
#include <hip/hip_runtime.h>

#define N_NODES 50000
#define NEDGE 800000
#define CONVB 1563   // ceil(800000 float4s / 512)
#define HISTB 391    // ceil(200000 int4s / 512)
#define NSCAN 98     // ceil(50000 / 512)
#define NTILES 782   // ceil(50000 / 64)

// ws layout:
//   fb     [N_NODES*64]  ushort (bf16 features)  6.4 MB
//   cnt    [N_NODES]     int  (zeroed via memset)
//   offs   [N_NODES+1]   int
//   cursor [N_NODES]     int
//   scol   [NEDGE]       int

__device__ __forceinline__ unsigned short f2bf(float x) {
    unsigned int u = __float_as_uint(x);
    unsigned int r = (u + 0x7FFFu + ((u >> 16) & 1u)) >> 16;  // RNE
    return (unsigned short)r;
}

__device__ __forceinline__ void acc8(float* a, uint4 v) {
    a[0] += __uint_as_float(v.x << 16);
    a[1] += __uint_as_float(v.x & 0xffff0000u);
    a[2] += __uint_as_float(v.y << 16);
    a[3] += __uint_as_float(v.y & 0xffff0000u);
    a[4] += __uint_as_float(v.z << 16);
    a[5] += __uint_as_float(v.z & 0xffff0000u);
    a[6] += __uint_as_float(v.w << 16);
    a[7] += __uint_as_float(v.w & 0xffff0000u);
}

// K1: feat->bf16 convert (blocks 0..CONVB-1)  ||  histogram (blocks CONVB..)
__global__ __launch_bounds__(512) void conv_hist_kernel(
    const float* __restrict__ feat, unsigned short* __restrict__ fb,
    const int* __restrict__ row, int* __restrict__ cnt) {
    int b = blockIdx.x;
    if (b < CONVB) {
        int i = b * 512 + threadIdx.x;
        if (i < N_NODES * 16) {
            float4 v = ((const float4*)feat)[i];
            ushort4 o;
            o.x = f2bf(v.x); o.y = f2bf(v.y); o.z = f2bf(v.z); o.w = f2bf(v.w);
            ((ushort4*)fb)[i] = o;
        }
    } else {
        int i = (b - CONVB) * 512 + threadIdx.x;
        if (i < NEDGE / 4) {
            int4 r = ((const int4*)row)[i];
            atomicAdd(&cnt[r.x], 1);
            atomicAdd(&cnt[r.y], 1);
            atomicAdd(&cnt[r.z], 1);
            atomicAdd(&cnt[r.w], 1);
        }
    }
}

// K2: single-kernel exclusive scan; each block self-computes its prefix
// by re-reading cnt[0 .. b*512) (coalesced, L2-hot, ~10 MB total).
__global__ __launch_bounds__(512) void scan_kernel(
    const int* __restrict__ cnt, int* __restrict__ offs, int* __restrict__ cursor) {
    __shared__ int ibuf[512];
    __shared__ int wpart[8];
    __shared__ int s_bp;
    const int b = blockIdx.x;
    const int t = threadIdx.x;
    const int lim = b * 512;

    // prefix over preceding chunks
    int part = 0;
    for (int i = t; i < lim; i += 512) part += cnt[i];
#pragma unroll
    for (int off = 32; off > 0; off >>= 1) part += __shfl_down(part, off, 64);
    if ((t & 63) == 0) wpart[t >> 6] = part;
    __syncthreads();
    if (t == 0) {
        int tot = 0;
#pragma unroll
        for (int w = 0; w < 8; w++) tot += wpart[w];
        s_bp = tot;
    }

    // local inclusive scan of this chunk
    const int i = lim + t;
    int v = (i < N_NODES) ? cnt[i] : 0;
    ibuf[t] = v;
    __syncthreads();
    for (int off = 1; off < 512; off <<= 1) {
        int add = (t >= off) ? ibuf[t - off] : 0;
        __syncthreads();
        ibuf[t] += add;
        __syncthreads();
    }
    int excl = ibuf[t] - v;

    int o = s_bp + excl;
    if (i < N_NODES) { offs[i] = o; cursor[i] = o; }
    if (i == N_NODES - 1) offs[N_NODES] = o + v;
}

// K3: CSR build
__global__ __launch_bounds__(512) void reorder_kernel(
    const int* __restrict__ row, const int* __restrict__ col,
    int* __restrict__ cursor, int* __restrict__ scol) {
    int i = blockIdx.x * 512 + threadIdx.x;
    if (i < NEDGE / 4) {
        int4 r = ((const int4*)row)[i];
        int4 c = ((const int4*)col)[i];
        scol[atomicAdd(&cursor[r.x], 1)] = c.x;
        scol[atomicAdd(&cursor[r.y], 1)] = c.y;
        scol[atomicAdd(&cursor[r.z], 1)] = c.z;
        scol[atomicAdd(&cursor[r.w], 1)] = c.w;
    }
}

// K4: fused gather + normalize + concat + GEMM + ReLU.
// 64 nodes / 256 threads per block. LDS: cbuf 33.8 KB + sscol 8 KB = 42 KB
// -> 3 blocks/CU. Gather: 4 lanes/node, 32 B bf16 chunks, scol staged in LDS.
// GEMM: thread = 4 rows x 8 cols -> W traffic halved vs 2-row variant.
__global__ __launch_bounds__(256) void fused_kernel(
    const float* __restrict__ feat,
    const unsigned short* __restrict__ fb,
    const int* __restrict__ offs,
    const int* __restrict__ scol,
    const float* __restrict__ W,
    float* __restrict__ out) {
    __shared__ float cbuf[64][132];  // pad: 132 % 32 = 4
    __shared__ int sscol[2048];

    const int t = threadIdx.x;
    const int base = blockIdx.x * 64;
    const int nend = (base + 64 < N_NODES) ? base + 64 : N_NODES;

    // stage this tile's scol segment (avg ~1024 edges; 2048 cap is >20 sigma)
    const int st0 = offs[base];
    const int en0 = offs[nend];
    const int ecount = en0 - st0;
    const bool fits = (ecount <= 2048);
    if (fits) {
        for (int i = t; i < ecount; i += 256) sscol[i] = scol[st0 + i];
    }
    __syncthreads();

    // Gather: 4 lanes per node, each lane owns a 32-byte bf16 chunk (16 feats)
    {
        const int s = t >> 2;  // node slot 0..63
        const int g = t & 3;   // 32B chunk index
        int node = base + s;
        int st = 0, en = 0;
        if (node < N_NODES) { st = offs[node]; en = offs[node + 1]; }
        float a[16];
#pragma unroll
        for (int j = 0; j < 16; j++) a[j] = 0.f;

        if (fits) {
            int p = st - st0, pe = en - st0;
            for (; p + 2 <= pe; p += 2) {
                int c0 = sscol[p], c1 = sscol[p + 1];
                const uint4* r0p = (const uint4*)(fb + (size_t)c0 * 64) + g * 2;
                const uint4* r1p = (const uint4*)(fb + (size_t)c1 * 64) + g * 2;
                uint4 v00 = r0p[0], v01 = r0p[1];
                uint4 v10 = r1p[0], v11 = r1p[1];
                acc8(a, v00); acc8(a + 8, v01);
                acc8(a, v10); acc8(a + 8, v11);
            }
            if (p < pe) {
                int c0 = sscol[p];
                const uint4* r0p = (const uint4*)(fb + (size_t)c0 * 64) + g * 2;
                uint4 v00 = r0p[0], v01 = r0p[1];
                acc8(a, v00); acc8(a + 8, v01);
            }
        } else {  // never taken in practice
            for (int p = st; p < en; p++) {
                int c0 = scol[p];
                const uint4* r0p = (const uint4*)(fb + (size_t)c0 * 64) + g * 2;
                uint4 v00 = r0p[0], v01 = r0p[1];
                acc8(a, v00); acc8(a + 8, v01);
            }
        }

        float rd = 1.0f / (float)(en - st + 1);
#pragma unroll
        for (int q = 0; q < 4; q++) {
            *(float4*)&cbuf[s][64 + g * 16 + q * 4] =
                make_float4(a[q * 4] * rd, a[q * 4 + 1] * rd,
                            a[q * 4 + 2] * rd, a[q * 4 + 3] * rd);
        }
        // own features (fp32 exact)
#pragma unroll
        for (int q = 0; q < 4; q++) {
            float4 f = make_float4(0.f, 0.f, 0.f, 0.f);
            if (node < N_NODES) f = *(const float4*)&feat[node * 64 + g * 16 + q * 4];
            *(float4*)&cbuf[s][g * 16 + q * 4] = f;
        }
    }
    __syncthreads();

    // GEMM: thread computes 4 rows x 8 cols
    {
        const int g = t & 15;
        const int r0 = (t >> 4) * 4;

        float acc0[4][4];
        float acc1[4][4];
#pragma unroll
        for (int a = 0; a < 4; a++)
#pragma unroll
            for (int c = 0; c < 4; c++) { acc0[a][c] = 0.f; acc1[a][c] = 0.f; }

        for (int k = 0; k < 128; k += 4) {
            float4 cv[4];
#pragma unroll
            for (int a = 0; a < 4; a++) cv[a] = *(const float4*)&cbuf[r0 + a][k];
#pragma unroll
            for (int kk = 0; kk < 4; kk++) {
                float4 w0 = *(const float4*)&W[(k + kk) * 128 + g * 4];
                float4 w1 = *(const float4*)&W[(k + kk) * 128 + 64 + g * 4];
#pragma unroll
                for (int a = 0; a < 4; a++) {
                    float c = ((const float*)&cv[a])[kk];
                    acc0[a][0] += c * w0.x; acc0[a][1] += c * w0.y;
                    acc0[a][2] += c * w0.z; acc0[a][3] += c * w0.w;
                    acc1[a][0] += c * w1.x; acc1[a][1] += c * w1.y;
                    acc1[a][2] += c * w1.z; acc1[a][3] += c * w1.w;
                }
            }
        }

#pragma unroll
        for (int a = 0; a < 4; a++) {
            int gr = base + r0 + a;
            if (gr < N_NODES) {
                float4 o0 = make_float4(fmaxf(acc0[a][0], 0.f), fmaxf(acc0[a][1], 0.f),
                                        fmaxf(acc0[a][2], 0.f), fmaxf(acc0[a][3], 0.f));
                float4 o1 = make_float4(fmaxf(acc1[a][0], 0.f), fmaxf(acc1[a][1], 0.f),
                                        fmaxf(acc1[a][2], 0.f), fmaxf(acc1[a][3], 0.f));
                *(float4*)&out[gr * 128 + g * 4] = o0;
                *(float4*)&out[gr * 128 + 64 + g * 4] = o1;
            }
        }
    }
}

extern "C" void kernel_launch(void* const* d_in, const int* in_sizes, int n_in,
                              void* d_out, int out_size, void* d_ws, size_t ws_size,
                              hipStream_t stream) {
    const float* feat = (const float*)d_in[0];
    const int* row = (const int*)d_in[1];
    const int* col = (const int*)d_in[2];
    const float* W = (const float*)d_in[3];
    float* out = (float*)d_out;

    unsigned short* fb = (unsigned short*)d_ws;  // 6.4 MB
    int* cnt = (int*)((char*)d_ws + (size_t)N_NODES * 64 * 2);
    int* offs = cnt + N_NODES;       // N_NODES+1
    int* cursor = offs + N_NODES + 1;
    int* scol = cursor + N_NODES;

    hipMemsetAsync(cnt, 0, N_NODES * sizeof(int), stream);
    conv_hist_kernel<<<CONVB + HISTB, 512, 0, stream>>>(feat, fb, row, cnt);
    scan_kernel<<<NSCAN, 512, 0, stream>>>(cnt, offs, cursor);
    reorder_kernel<<<HISTB, 512, 0, stream>>>(row, col, cursor, scol);
    fused_kernel<<<NTILES, 256, 0, stream>>>(feat, fb, offs, scol, W, out);
}

// Round 9
// 201.706 us; speedup vs baseline: 1.9560x; 1.0971x over previous
//
#include <hip/hip_runtime.h>

#define N_NODES 50000
#define NEDGE 800000
#define CONVB 1563    // ceil(800000 float4s / 512)
#define HISTB 391     // ceil(200000 int4s / 512)
#define NSCAN 98      // ceil(50000 / 512); also the bucket count (512 rows each)
#define NTILES 782    // ceil(50000 / 64)
#define R1B 196       // ceil(200000 int4s / 1024)
#define BCAP 10240    // per-bucket edge cap (mean 8192, sigma ~90)

// ws layout (ints after fb):
//   fb    [N_NODES*64]  ushort (bf16 features)  6.4 MB
//   cnt   [N_NODES]
//   offs  [N_NODES+1]
//   bcur  [NSCAN]       bucket write cursors (init = offs[b*512] by scan)
//   scol  [NEDGE]       final CSR col array
//   tbuf  [NEDGE]       packed (localrow<<17)|col, bucket-partitioned

__device__ __forceinline__ unsigned short f2bf(float x) {
    unsigned int u = __float_as_uint(x);
    unsigned int r = (u + 0x7FFFu + ((u >> 16) & 1u)) >> 16;  // RNE
    return (unsigned short)r;
}

__device__ __forceinline__ void acc8(float* a, uint4 v) {
    a[0] += __uint_as_float(v.x << 16);
    a[1] += __uint_as_float(v.x & 0xffff0000u);
    a[2] += __uint_as_float(v.y << 16);
    a[3] += __uint_as_float(v.y & 0xffff0000u);
    a[4] += __uint_as_float(v.z << 16);
    a[5] += __uint_as_float(v.z & 0xffff0000u);
    a[6] += __uint_as_float(v.w << 16);
    a[7] += __uint_as_float(v.w & 0xffff0000u);
}

// K1: feat->bf16 convert (blocks < CONVB)  ||  histogram (blocks >= CONVB)
__global__ __launch_bounds__(512) void conv_hist_kernel(
    const float* __restrict__ feat, unsigned short* __restrict__ fb,
    const int* __restrict__ row, int* __restrict__ cnt) {
    int b = blockIdx.x;
    if (b < CONVB) {
        int i = b * 512 + threadIdx.x;
        if (i < N_NODES * 16) {
            float4 v = ((const float4*)feat)[i];
            ushort4 o;
            o.x = f2bf(v.x); o.y = f2bf(v.y); o.z = f2bf(v.z); o.w = f2bf(v.w);
            ((ushort4*)fb)[i] = o;
        }
    } else {
        int i = (b - CONVB) * 512 + threadIdx.x;
        if (i < NEDGE / 4) {
            int4 r = ((const int4*)row)[i];
            atomicAdd(&cnt[r.x], 1);
            atomicAdd(&cnt[r.y], 1);
            atomicAdd(&cnt[r.z], 1);
            atomicAdd(&cnt[r.w], 1);
        }
    }
}

// K2: exclusive scan; block b self-computes its prefix; also seeds bcur[b].
__global__ __launch_bounds__(512) void scan_kernel(
    const int* __restrict__ cnt, int* __restrict__ offs, int* __restrict__ bcur) {
    __shared__ int ibuf[512];
    __shared__ int wpart[8];
    __shared__ int s_bp;
    const int b = blockIdx.x;
    const int t = threadIdx.x;
    const int lim = b * 512;

    int part = 0;
    for (int i = t; i < lim; i += 512) part += cnt[i];
#pragma unroll
    for (int off = 32; off > 0; off >>= 1) part += __shfl_down(part, off, 64);
    if ((t & 63) == 0) wpart[t >> 6] = part;
    __syncthreads();
    if (t == 0) {
        int tot = 0;
#pragma unroll
        for (int w = 0; w < 8; w++) tot += wpart[w];
        s_bp = tot;
        bcur[b] = tot;  // bucket b's base = offs[b*512]
    }

    const int i = lim + t;
    int v = (i < N_NODES) ? cnt[i] : 0;
    ibuf[t] = v;
    __syncthreads();
    for (int off = 1; off < 512; off <<= 1) {
        int add = (t >= off) ? ibuf[t - off] : 0;
        __syncthreads();
        ibuf[t] += add;
        __syncthreads();
    }
    int excl = ibuf[t] - v;

    int o = s_bp + excl;
    if (i < N_NODES) offs[i] = o;
    if (i == N_NODES - 1) offs[N_NODES] = o + v;
}

// K3 (R1): partition edges into 98 buckets of 512 rows. Per-block LDS hist,
// one global atomicAdd per bucket reserves a contiguous run in tbuf, then
// packed (localrow<<17)|col written into block-private runs (dense lines).
__global__ __launch_bounds__(256) void part_kernel(
    const int* __restrict__ row, const int* __restrict__ col,
    int* __restrict__ bcur, unsigned int* __restrict__ tbuf) {
    __shared__ int hist[NSCAN];
    __shared__ int rbase[NSCAN];
    __shared__ int lcur[NSCAN];

    const int t = threadIdx.x;
    for (int i = t; i < NSCAN; i += 256) hist[i] = 0;
    __syncthreads();

    const int base4 = blockIdx.x * 1024;  // int4 index base (4096 edges/block)
    int4 rv[4], cv[4];
#pragma unroll
    for (int k = 0; k < 4; k++) {
        int i4 = base4 + k * 256 + t;
        if (i4 < NEDGE / 4) {
            rv[k] = ((const int4*)row)[i4];
            cv[k] = ((const int4*)col)[i4];
            atomicAdd(&hist[rv[k].x >> 9], 1);
            atomicAdd(&hist[rv[k].y >> 9], 1);
            atomicAdd(&hist[rv[k].z >> 9], 1);
            atomicAdd(&hist[rv[k].w >> 9], 1);
        } else {
            rv[k] = make_int4(-1, -1, -1, -1);
            cv[k] = make_int4(0, 0, 0, 0);
        }
    }
    __syncthreads();

    for (int i = t; i < NSCAN; i += 256) {
        rbase[i] = atomicAdd(&bcur[i], hist[i]);
        lcur[i] = 0;
    }
    __syncthreads();

#pragma unroll
    for (int k = 0; k < 4; k++) {
        if (rv[k].x < 0) continue;
        int rr[4] = {rv[k].x, rv[k].y, rv[k].z, rv[k].w};
        int cc[4] = {cv[k].x, cv[k].y, cv[k].z, cv[k].w};
#pragma unroll
        for (int j = 0; j < 4; j++) {
            int bk = rr[j] >> 9;
            int pos = rbase[bk] + atomicAdd(&lcur[bk], 1);
            tbuf[pos] = ((unsigned int)(rr[j] & 511) << 17) | (unsigned int)cc[j];
        }
    }
}

// K4 (R2): per-bucket LDS counting-sort -> coalesced scol writes.
__global__ __launch_bounds__(256) void bucket_sort_kernel(
    const int* __restrict__ offs, const unsigned int* __restrict__ tbuf,
    int* __restrict__ scol) {
    __shared__ int curs[512];
    __shared__ int sstage[BCAP];

    const int b = blockIdx.x;
    const int t = threadIdx.x;
    const int r0 = b * 512;
    const int r1 = (r0 + 512 < N_NODES) ? r0 + 512 : N_NODES;
    const int base = offs[r0];
    const int end = offs[r1];
    const int n = end - base;

    for (int lr = t; lr < 512; lr += 256)
        curs[lr] = (r0 + lr < r1) ? offs[r0 + lr] - base : n;
    __syncthreads();

    if (n <= BCAP) {
        for (int i = t; i < n; i += 256) {
            unsigned int p = tbuf[base + i];
            int lr = p >> 17;
            int c = (int)(p & 0x1FFFFu);
            int pos = atomicAdd(&curs[lr], 1);
            sstage[pos] = c;
        }
        __syncthreads();
        for (int i = t; i < n; i += 256) scol[base + i] = sstage[i];
    } else {  // >22 sigma; correctness fallback
        for (int i = t; i < n; i += 256) {
            unsigned int p = tbuf[base + i];
            int lr = p >> 17;
            int c = (int)(p & 0x1FFFFu);
            int pos = atomicAdd(&curs[lr], 1);
            scol[base + pos] = c;
        }
    }
}

// K5: fused gather + normalize + concat + GEMM + ReLU (unchanged from R8).
__global__ __launch_bounds__(256) void fused_kernel(
    const float* __restrict__ feat,
    const unsigned short* __restrict__ fb,
    const int* __restrict__ offs,
    const int* __restrict__ scol,
    const float* __restrict__ W,
    float* __restrict__ out) {
    __shared__ float cbuf[64][132];  // pad: 132 % 32 = 4
    __shared__ int sscol[2048];

    const int t = threadIdx.x;
    const int base = blockIdx.x * 64;
    const int nend = (base + 64 < N_NODES) ? base + 64 : N_NODES;

    const int st0 = offs[base];
    const int en0 = offs[nend];
    const int ecount = en0 - st0;
    const bool fits = (ecount <= 2048);
    if (fits) {
        for (int i = t; i < ecount; i += 256) sscol[i] = scol[st0 + i];
    }
    __syncthreads();

    {
        const int s = t >> 2;  // node slot 0..63
        const int g = t & 3;   // 32B chunk index
        int node = base + s;
        int st = 0, en = 0;
        if (node < N_NODES) { st = offs[node]; en = offs[node + 1]; }
        float a[16];
#pragma unroll
        for (int j = 0; j < 16; j++) a[j] = 0.f;

        if (fits) {
            int p = st - st0, pe = en - st0;
            for (; p + 2 <= pe; p += 2) {
                int c0 = sscol[p], c1 = sscol[p + 1];
                const uint4* r0p = (const uint4*)(fb + (size_t)c0 * 64) + g * 2;
                const uint4* r1p = (const uint4*)(fb + (size_t)c1 * 64) + g * 2;
                uint4 v00 = r0p[0], v01 = r0p[1];
                uint4 v10 = r1p[0], v11 = r1p[1];
                acc8(a, v00); acc8(a + 8, v01);
                acc8(a, v10); acc8(a + 8, v11);
            }
            if (p < pe) {
                int c0 = sscol[p];
                const uint4* r0p = (const uint4*)(fb + (size_t)c0 * 64) + g * 2;
                uint4 v00 = r0p[0], v01 = r0p[1];
                acc8(a, v00); acc8(a + 8, v01);
            }
        } else {
            for (int p = st; p < en; p++) {
                int c0 = scol[p];
                const uint4* r0p = (const uint4*)(fb + (size_t)c0 * 64) + g * 2;
                uint4 v00 = r0p[0], v01 = r0p[1];
                acc8(a, v00); acc8(a + 8, v01);
            }
        }

        float rd = 1.0f / (float)(en - st + 1);
#pragma unroll
        for (int q = 0; q < 4; q++) {
            *(float4*)&cbuf[s][64 + g * 16 + q * 4] =
                make_float4(a[q * 4] * rd, a[q * 4 + 1] * rd,
                            a[q * 4 + 2] * rd, a[q * 4 + 3] * rd);
        }
#pragma unroll
        for (int q = 0; q < 4; q++) {
            float4 f = make_float4(0.f, 0.f, 0.f, 0.f);
            if (node < N_NODES) f = *(const float4*)&feat[node * 64 + g * 16 + q * 4];
            *(float4*)&cbuf[s][g * 16 + q * 4] = f;
        }
    }
    __syncthreads();

    {
        const int g = t & 15;
        const int r0 = (t >> 4) * 4;

        float acc0[4][4];
        float acc1[4][4];
#pragma unroll
        for (int a = 0; a < 4; a++)
#pragma unroll
            for (int c = 0; c < 4; c++) { acc0[a][c] = 0.f; acc1[a][c] = 0.f; }

        for (int k = 0; k < 128; k += 4) {
            float4 cv[4];
#pragma unroll
            for (int a = 0; a < 4; a++) cv[a] = *(const float4*)&cbuf[r0 + a][k];
#pragma unroll
            for (int kk = 0; kk < 4; kk++) {
                float4 w0 = *(const float4*)&W[(k + kk) * 128 + g * 4];
                float4 w1 = *(const float4*)&W[(k + kk) * 128 + 64 + g * 4];
#pragma unroll
                for (int a = 0; a < 4; a++) {
                    float c = ((const float*)&cv[a])[kk];
                    acc0[a][0] += c * w0.x; acc0[a][1] += c * w0.y;
                    acc0[a][2] += c * w0.z; acc0[a][3] += c * w0.w;
                    acc1[a][0] += c * w1.x; acc1[a][1] += c * w1.y;
                    acc1[a][2] += c * w1.z; acc1[a][3] += c * w1.w;
                }
            }
        }

#pragma unroll
        for (int a = 0; a < 4; a++) {
            int gr = base + r0 + a;
            if (gr < N_NODES) {
                float4 o0 = make_float4(fmaxf(acc0[a][0], 0.f), fmaxf(acc0[a][1], 0.f),
                                        fmaxf(acc0[a][2], 0.f), fmaxf(acc0[a][3], 0.f));
                float4 o1 = make_float4(fmaxf(acc1[a][0], 0.f), fmaxf(acc1[a][1], 0.f),
                                        fmaxf(acc1[a][2], 0.f), fmaxf(acc1[a][3], 0.f));
                *(float4*)&out[gr * 128 + g * 4] = o0;
                *(float4*)&out[gr * 128 + 64 + g * 4] = o1;
            }
        }
    }
}

extern "C" void kernel_launch(void* const* d_in, const int* in_sizes, int n_in,
                              void* d_out, int out_size, void* d_ws, size_t ws_size,
                              hipStream_t stream) {
    const float* feat = (const float*)d_in[0];
    const int* row = (const int*)d_in[1];
    const int* col = (const int*)d_in[2];
    const float* W = (const float*)d_in[3];
    float* out = (float*)d_out;

    unsigned short* fb = (unsigned short*)d_ws;  // 6.4 MB
    int* cnt = (int*)((char*)d_ws + (size_t)N_NODES * 64 * 2);
    int* offs = cnt + N_NODES;        // N_NODES+1
    int* bcur = offs + N_NODES + 1;   // NSCAN
    int* scol = bcur + NSCAN;         // NEDGE
    unsigned int* tbuf = (unsigned int*)(scol + NEDGE);  // NEDGE

    hipMemsetAsync(cnt, 0, N_NODES * sizeof(int), stream);
    conv_hist_kernel<<<CONVB + HISTB, 512, 0, stream>>>(feat, fb, row, cnt);
    scan_kernel<<<NSCAN, 512, 0, stream>>>(cnt, offs, bcur);
    part_kernel<<<R1B, 256, 0, stream>>>(row, col, bcur, tbuf);
    bucket_sort_kernel<<<NSCAN, 256, 0, stream>>>(offs, tbuf, scol);
    fused_kernel<<<NTILES, 256, 0, stream>>>(feat, fb, offs, scol, W, out);
}

// Round 10
// 144.642 us; speedup vs baseline: 2.7277x; 1.3945x over previous
//
#include <hip/hip_runtime.h>

#define N_NODES 50000
#define NEDGE 800000
#define NEDGE4 (NEDGE / 4)   // 200000 int4s
#define CONVB 1563           // ceil(800000 float4 / 512)
#define PARTB 98             // ceil(200000 int4 / (512*4))
#define NBUCKET 782          // one bucket per 64-node fused tile
#define TCAP 2048            // per-tile edge cap (mean 1024, sd 32 -> 32 sigma)

// ws layout:
//   fb    [N_NODES*64] ushort (bf16 features)   6.4 MB
//   bhist [NBUCKET]    int  (zeroed via memset)
//   bbase [NBUCKET+1]  int  exclusive scan of bhist
//   bcur  [NBUCKET]    int  partition cursors
//   tbuf  [NEDGE]      uint packed (localrow<<17)|col, bucket-partitioned

__device__ __forceinline__ unsigned short f2bf(float x) {
    unsigned int u = __float_as_uint(x);
    unsigned int r = (u + 0x7FFFu + ((u >> 16) & 1u)) >> 16;  // RNE
    return (unsigned short)r;
}

__device__ __forceinline__ void acc8(float* a, uint4 v) {
    a[0] += __uint_as_float(v.x << 16);
    a[1] += __uint_as_float(v.x & 0xffff0000u);
    a[2] += __uint_as_float(v.y << 16);
    a[3] += __uint_as_float(v.y & 0xffff0000u);
    a[4] += __uint_as_float(v.z << 16);
    a[5] += __uint_as_float(v.z & 0xffff0000u);
    a[6] += __uint_as_float(v.w << 16);
    a[7] += __uint_as_float(v.w & 0xffff0000u);
}

// K1: feat->bf16 convert (blocks < CONVB) || bucket histogram (blocks >= CONVB)
__global__ __launch_bounds__(512) void conv_bhist_kernel(
    const float* __restrict__ feat, unsigned short* __restrict__ fb,
    const int* __restrict__ row, int* __restrict__ bhist) {
    __shared__ int hist[NBUCKET];
    const int b = blockIdx.x;
    const int t = threadIdx.x;
    if (b < CONVB) {
        int i = b * 512 + t;
        if (i < N_NODES * 16) {
            float4 v = ((const float4*)feat)[i];
            ushort4 o;
            o.x = f2bf(v.x); o.y = f2bf(v.y); o.z = f2bf(v.z); o.w = f2bf(v.w);
            ((ushort4*)fb)[i] = o;
        }
    } else {
        for (int i = t; i < NBUCKET; i += 512) hist[i] = 0;
        __syncthreads();
        const int base4 = (b - CONVB) * 2048;
#pragma unroll
        for (int k = 0; k < 4; k++) {
            int i4 = base4 + k * 512 + t;
            if (i4 < NEDGE4) {
                int4 r = ((const int4*)row)[i4];
                atomicAdd(&hist[r.x >> 6], 1);
                atomicAdd(&hist[r.y >> 6], 1);
                atomicAdd(&hist[r.z >> 6], 1);
                atomicAdd(&hist[r.w >> 6], 1);
            }
        }
        __syncthreads();
        for (int i = t; i < NBUCKET; i += 512)
            if (hist[i]) atomicAdd(&bhist[i], hist[i]);
    }
}

// K2: single-block exclusive scan of 782 bucket counts
__global__ __launch_bounds__(1024) void bscan_kernel(
    const int* __restrict__ bhist, int* __restrict__ bbase, int* __restrict__ bcur) {
    __shared__ int buf[1024];
    const int t = threadIdx.x;
    int v = (t < NBUCKET) ? bhist[t] : 0;
    buf[t] = v;
    __syncthreads();
    for (int off = 1; off < 1024; off <<= 1) {
        int add = (t >= off) ? buf[t - off] : 0;
        __syncthreads();
        buf[t] += add;
        __syncthreads();
    }
    int excl = buf[t] - v;
    if (t < NBUCKET) { bbase[t] = excl; bcur[t] = excl; }
    if (t == NBUCKET - 1) bbase[NBUCKET] = excl + v;
}

// K3: partition edges into 782 tile-buckets. Per-block LDS hist, one global
// atomicAdd per bucket reserves a run in tbuf, packed writes (dense-ish runs).
__global__ __launch_bounds__(512) void part_kernel(
    const int* __restrict__ row, const int* __restrict__ col,
    int* __restrict__ bcur, unsigned int* __restrict__ tbuf) {
    __shared__ int hist[NBUCKET];
    __shared__ int rbase[NBUCKET];
    __shared__ int lcur[NBUCKET];
    const int t = threadIdx.x;
    for (int i = t; i < NBUCKET; i += 512) hist[i] = 0;
    __syncthreads();

    const int base4 = blockIdx.x * 2048;  // 8192 edges per block
    int4 rv[4], cv[4];
#pragma unroll
    for (int k = 0; k < 4; k++) {
        int i4 = base4 + k * 512 + t;
        if (i4 < NEDGE4) {
            rv[k] = ((const int4*)row)[i4];
            cv[k] = ((const int4*)col)[i4];
            atomicAdd(&hist[rv[k].x >> 6], 1);
            atomicAdd(&hist[rv[k].y >> 6], 1);
            atomicAdd(&hist[rv[k].z >> 6], 1);
            atomicAdd(&hist[rv[k].w >> 6], 1);
        } else {
            rv[k] = make_int4(-1, -1, -1, -1);
            cv[k] = make_int4(0, 0, 0, 0);
        }
    }
    __syncthreads();

    for (int i = t; i < NBUCKET; i += 512) {
        rbase[i] = atomicAdd(&bcur[i], hist[i]);
        lcur[i] = 0;
    }
    __syncthreads();

#pragma unroll
    for (int k = 0; k < 4; k++) {
        if (rv[k].x < 0) continue;
        int rr[4] = {rv[k].x, rv[k].y, rv[k].z, rv[k].w};
        int cc[4] = {cv[k].x, cv[k].y, cv[k].z, cv[k].w};
#pragma unroll
        for (int j = 0; j < 4; j++) {
            int bk = rr[j] >> 6;
            int pos = rbase[bk] + atomicAdd(&lcur[bk], 1);
            tbuf[pos] = ((unsigned int)(rr[j] & 63) << 17) | (unsigned int)cc[j];
        }
    }
}

// K4: fused in-LDS counting-sort + gather + normalize + concat + GEMM + ReLU.
// 64 nodes / 256 threads / block. tpack overlays cbuf (dead until gather).
__global__ __launch_bounds__(256) void fused_kernel(
    const float* __restrict__ feat,
    const unsigned short* __restrict__ fb,
    const int* __restrict__ bbase,
    const unsigned int* __restrict__ tbuf,
    const float* __restrict__ W,
    float* __restrict__ out) {
    __shared__ float cbuf[64][132];  // 33.8 KB; first 2048 ints reused as tpack
    __shared__ int sscol[TCAP];      // 8 KB
    __shared__ int nhist[64];
    __shared__ int nst[65];
    __shared__ int ncurs[64];

    const int t = threadIdx.x;
    const int blk = blockIdx.x;
    const int base = blk * 64;
    const int st0 = bbase[blk];
    const int en0 = bbase[blk + 1];
    const int ecount = en0 - st0;
    const bool fits = (ecount <= TCAP);

    const int s = t >> 2;  // node slot 0..63
    const int g = t & 3;   // 32-byte bf16 chunk index
    const int node = base + s;

    float a[16];
#pragma unroll
    for (int j = 0; j < 16; j++) a[j] = 0.f;
    int deg = 0;

    if (fits) {
        int* tpack = (int*)&cbuf[0][0];
        for (int i = t; i < ecount; i += 256) tpack[i] = (int)tbuf[st0 + i];
        if (t < 64) nhist[t] = 0;
        __syncthreads();
        for (int i = t; i < ecount; i += 256) atomicAdd(&nhist[tpack[i] >> 17], 1);
        __syncthreads();
        if (t < 64) {  // exclusive scan of 64 counts in wave 0
            int v = nhist[t];
            int incl = v;
#pragma unroll
            for (int off = 1; off < 64; off <<= 1) {
                int u = __shfl_up(incl, off, 64);
                if (t >= off) incl += u;
            }
            nst[t + 1] = incl;
            if (t == 0) nst[0] = 0;
            ncurs[t] = incl - v;
        }
        __syncthreads();
        for (int i = t; i < ecount; i += 256) {
            int p = tpack[i];
            int lr = p >> 17;
            int pos = atomicAdd(&ncurs[lr], 1);
            sscol[pos] = p & 0x1FFFF;
        }
        __syncthreads();

        // Gather: 4 lanes/node, 32 B bf16 chunks, indices from LDS
        int st = nst[s], en = nst[s + 1];
        deg = en - st;
        int p = st;
        for (; p + 2 <= en; p += 2) {
            int c0 = sscol[p], c1 = sscol[p + 1];
            const uint4* r0p = (const uint4*)(fb + (size_t)c0 * 64) + g * 2;
            const uint4* r1p = (const uint4*)(fb + (size_t)c1 * 64) + g * 2;
            uint4 v00 = r0p[0], v01 = r0p[1];
            uint4 v10 = r1p[0], v11 = r1p[1];
            acc8(a, v00); acc8(a + 8, v01);
            acc8(a, v10); acc8(a + 8, v11);
        }
        if (p < en) {
            int c0 = sscol[p];
            const uint4* r0p = (const uint4*)(fb + (size_t)c0 * 64) + g * 2;
            uint4 v00 = r0p[0], v01 = r0p[1];
            acc8(a, v00); acc8(a + 8, v01);
        }
    } else {  // >32 sigma; correctness-only scan-filter from global tbuf
        __syncthreads();
        for (int p = st0; p < en0; p++) {
            unsigned int pk = tbuf[p];
            if ((int)(pk >> 17) == s) {
                deg++;
                int c0 = (int)(pk & 0x1FFFFu);
                const uint4* r0p = (const uint4*)(fb + (size_t)c0 * 64) + g * 2;
                uint4 v00 = r0p[0], v01 = r0p[1];
                acc8(a, v00); acc8(a + 8, v01);
            }
        }
        __syncthreads();
    }

    // Write combined tile: own fp32 feats [0,64) + normalized neigh [64,128)
    {
        float rd = 1.0f / (float)(deg + 1);
#pragma unroll
        for (int q = 0; q < 4; q++) {
            *(float4*)&cbuf[s][64 + g * 16 + q * 4] =
                make_float4(a[q * 4] * rd, a[q * 4 + 1] * rd,
                            a[q * 4 + 2] * rd, a[q * 4 + 3] * rd);
        }
#pragma unroll
        for (int q = 0; q < 4; q++) {
            float4 f = make_float4(0.f, 0.f, 0.f, 0.f);
            if (node < N_NODES) f = *(const float4*)&feat[node * 64 + g * 16 + q * 4];
            *(float4*)&cbuf[s][g * 16 + q * 4] = f;
        }
    }
    __syncthreads();

    // GEMM: thread computes 4 rows x 8 cols
    {
        const int gg = t & 15;
        const int r0 = (t >> 4) * 4;

        float acc0[4][4];
        float acc1[4][4];
#pragma unroll
        for (int aa = 0; aa < 4; aa++)
#pragma unroll
            for (int c = 0; c < 4; c++) { acc0[aa][c] = 0.f; acc1[aa][c] = 0.f; }

        for (int k = 0; k < 128; k += 4) {
            float4 cv[4];
#pragma unroll
            for (int aa = 0; aa < 4; aa++) cv[aa] = *(const float4*)&cbuf[r0 + aa][k];
#pragma unroll
            for (int kk = 0; kk < 4; kk++) {
                float4 w0 = *(const float4*)&W[(k + kk) * 128 + gg * 4];
                float4 w1 = *(const float4*)&W[(k + kk) * 128 + 64 + gg * 4];
#pragma unroll
                for (int aa = 0; aa < 4; aa++) {
                    float c = ((const float*)&cv[aa])[kk];
                    acc0[aa][0] += c * w0.x; acc0[aa][1] += c * w0.y;
                    acc0[aa][2] += c * w0.z; acc0[aa][3] += c * w0.w;
                    acc1[aa][0] += c * w1.x; acc1[aa][1] += c * w1.y;
                    acc1[aa][2] += c * w1.z; acc1[aa][3] += c * w1.w;
                }
            }
        }

#pragma unroll
        for (int aa = 0; aa < 4; aa++) {
            int gr = base + r0 + aa;
            if (gr < N_NODES) {
                float4 o0 = make_float4(fmaxf(acc0[aa][0], 0.f), fmaxf(acc0[aa][1], 0.f),
                                        fmaxf(acc0[aa][2], 0.f), fmaxf(acc0[aa][3], 0.f));
                float4 o1 = make_float4(fmaxf(acc1[aa][0], 0.f), fmaxf(acc1[aa][1], 0.f),
                                        fmaxf(acc1[aa][2], 0.f), fmaxf(acc1[aa][3], 0.f));
                *(float4*)&out[gr * 128 + gg * 4] = o0;
                *(float4*)&out[gr * 128 + 64 + gg * 4] = o1;
            }
        }
    }
}

extern "C" void kernel_launch(void* const* d_in, const int* in_sizes, int n_in,
                              void* d_out, int out_size, void* d_ws, size_t ws_size,
                              hipStream_t stream) {
    const float* feat = (const float*)d_in[0];
    const int* row = (const int*)d_in[1];
    const int* col = (const int*)d_in[2];
    const float* W = (const float*)d_in[3];
    float* out = (float*)d_out;

    unsigned short* fb = (unsigned short*)d_ws;  // 6.4 MB
    int* bhist = (int*)((char*)d_ws + (size_t)N_NODES * 64 * 2);
    int* bbase = bhist + NBUCKET;      // NBUCKET+1
    int* bcur = bbase + NBUCKET + 1;   // NBUCKET
    unsigned int* tbuf = (unsigned int*)(bcur + NBUCKET);  // NEDGE

    hipMemsetAsync(bhist, 0, NBUCKET * sizeof(int), stream);
    conv_bhist_kernel<<<CONVB + PARTB, 512, 0, stream>>>(feat, fb, row, bhist);
    bscan_kernel<<<1, 1024, 0, stream>>>(bhist, bbase, bcur);
    part_kernel<<<PARTB, 512, 0, stream>>>(row, col, bcur, tbuf);
    fused_kernel<<<NBUCKET, 256, 0, stream>>>(feat, fb, bbase, tbuf, W, out);
}

// Round 11
// 127.404 us; speedup vs baseline: 3.0967x; 1.1353x over previous
//
#include <hip/hip_runtime.h>

#define N_NODES 50000
#define NEDGE 800000
#define NEDGE4 (NEDGE / 4)   // 200000 int4s
#define CONVB 1563           // ceil(800000 float4 / 512)
#define PARTB 98             // ceil(200000 int4 / (512*4))
#define NBUCKET 782          // one bucket per 64-node fused tile
#define TCAP 2048            // per-tile edge cap (mean 1024, sd 32)

typedef __attribute__((ext_vector_type(8))) short bf16x8;
typedef __attribute__((ext_vector_type(4))) float f32x4;

// ws layout:
//   fb    [N_NODES*64]  ushort bf16 features     6.4 MB
//   wbs   [16384]       ushort W in B-fragment layout (32 KB)
//   bhist [NBUCKET]     int (zeroed via memset)
//   bbase [NBUCKET+1]   int
//   bcur  [NBUCKET]     int
//   tbuf  [NEDGE]       uint packed (localrow<<17)|col

__device__ __forceinline__ unsigned short f2bf(float x) {
    unsigned int u = __float_as_uint(x);
    unsigned int r = (u + 0x7FFFu + ((u >> 16) & 1u)) >> 16;  // RNE
    return (unsigned short)r;
}

__device__ __forceinline__ void acc8(float* a, uint4 v) {
    a[0] += __uint_as_float(v.x << 16);
    a[1] += __uint_as_float(v.x & 0xffff0000u);
    a[2] += __uint_as_float(v.y << 16);
    a[3] += __uint_as_float(v.y & 0xffff0000u);
    a[4] += __uint_as_float(v.z << 16);
    a[5] += __uint_as_float(v.z & 0xffff0000u);
    a[6] += __uint_as_float(v.w << 16);
    a[7] += __uint_as_float(v.w & 0xffff0000u);
}

// K1: feat->bf16 convert (blocks < CONVB) || bucket histogram (blocks >= CONVB)
__global__ __launch_bounds__(512) void conv_bhist_kernel(
    const float* __restrict__ feat, unsigned short* __restrict__ fb,
    const int* __restrict__ row, int* __restrict__ bhist) {
    __shared__ int hist[NBUCKET];
    const int b = blockIdx.x;
    const int t = threadIdx.x;
    if (b < CONVB) {
        int i = b * 512 + t;
        if (i < N_NODES * 16) {
            float4 v = ((const float4*)feat)[i];
            ushort4 o;
            o.x = f2bf(v.x); o.y = f2bf(v.y); o.z = f2bf(v.z); o.w = f2bf(v.w);
            ((ushort4*)fb)[i] = o;
        }
    } else {
        for (int i = t; i < NBUCKET; i += 512) hist[i] = 0;
        __syncthreads();
        const int base4 = (b - CONVB) * 2048;
#pragma unroll
        for (int k = 0; k < 4; k++) {
            int i4 = base4 + k * 512 + t;
            if (i4 < NEDGE4) {
                int4 r = ((const int4*)row)[i4];
                atomicAdd(&hist[r.x >> 6], 1);
                atomicAdd(&hist[r.y >> 6], 1);
                atomicAdd(&hist[r.z >> 6], 1);
                atomicAdd(&hist[r.w >> 6], 1);
            }
        }
        __syncthreads();
        for (int i = t; i < NBUCKET; i += 512)
            if (hist[i]) atomicAdd(&bhist[i], hist[i]);
    }
}

// K2: single-block scan of 782 bucket counts + W -> B-fragment bf16 pack.
// wbs[((nt*4+kblk)*64+lane)*8+j] = bf16(W[(kblk*32+(lane>>4)*8+j)*128 + nt*16+(lane&15)])
__global__ __launch_bounds__(1024) void bscan_kernel(
    const int* __restrict__ bhist, const float* __restrict__ W,
    int* __restrict__ bbase, int* __restrict__ bcur,
    unsigned short* __restrict__ wbs) {
    __shared__ int buf[1024];
    const int t = threadIdx.x;
    int v = (t < NBUCKET) ? bhist[t] : 0;
    buf[t] = v;
    __syncthreads();
    for (int off = 1; off < 1024; off <<= 1) {
        int add = (t >= off) ? buf[t - off] : 0;
        __syncthreads();
        buf[t] += add;
        __syncthreads();
    }
    int excl = buf[t] - v;
    if (t < NBUCKET) { bbase[t] = excl; bcur[t] = excl; }
    if (t == NBUCKET - 1) bbase[NBUCKET] = excl + v;

    for (int i = t; i < 16384; i += 1024) {
        int j = i & 7;
        int lane = (i >> 3) & 63;
        int kblk = (i >> 9) & 3;
        int nt = i >> 11;
        int k = kblk * 32 + (lane >> 4) * 8 + j;
        int n = nt * 16 + (lane & 15);
        wbs[i] = f2bf(W[k * 128 + n]);
    }
}

// K3: partition edges into 782 tile-buckets (packed writes into dense runs).
__global__ __launch_bounds__(512) void part_kernel(
    const int* __restrict__ row, const int* __restrict__ col,
    int* __restrict__ bcur, unsigned int* __restrict__ tbuf) {
    __shared__ int hist[NBUCKET];
    __shared__ int rbase[NBUCKET];
    __shared__ int lcur[NBUCKET];
    const int t = threadIdx.x;
    for (int i = t; i < NBUCKET; i += 512) hist[i] = 0;
    __syncthreads();

    const int base4 = blockIdx.x * 2048;  // 8192 edges per block
    int4 rv[4], cv[4];
#pragma unroll
    for (int k = 0; k < 4; k++) {
        int i4 = base4 + k * 512 + t;
        if (i4 < NEDGE4) {
            rv[k] = ((const int4*)row)[i4];
            cv[k] = ((const int4*)col)[i4];
            atomicAdd(&hist[rv[k].x >> 6], 1);
            atomicAdd(&hist[rv[k].y >> 6], 1);
            atomicAdd(&hist[rv[k].z >> 6], 1);
            atomicAdd(&hist[rv[k].w >> 6], 1);
        } else {
            rv[k] = make_int4(-1, -1, -1, -1);
            cv[k] = make_int4(0, 0, 0, 0);
        }
    }
    __syncthreads();

    for (int i = t; i < NBUCKET; i += 512) {
        rbase[i] = atomicAdd(&bcur[i], hist[i]);
        lcur[i] = 0;
    }
    __syncthreads();

#pragma unroll
    for (int k = 0; k < 4; k++) {
        if (rv[k].x < 0) continue;
        int rr[4] = {rv[k].x, rv[k].y, rv[k].z, rv[k].w};
        int cc[4] = {cv[k].x, cv[k].y, cv[k].z, cv[k].w};
#pragma unroll
        for (int j = 0; j < 4; j++) {
            int bk = rr[j] >> 6;
            int pos = rbase[bk] + atomicAdd(&lcur[bk], 1);
            tbuf[pos] = ((unsigned int)(rr[j] & 63) << 17) | (unsigned int)cc[j];
        }
    }
}

// K4: in-LDS counting-sort + bf16 gather (unroll 4) + MFMA GEMM + ReLU.
// 64 nodes / 256 threads. LDS: cbuf 17.4 KB (bf16, tpack overlays) + sscol 8 KB.
__global__ __launch_bounds__(256) void fused_kernel(
    const unsigned short* __restrict__ fb,
    const int* __restrict__ bbase,
    const unsigned int* __restrict__ tbuf,
    const unsigned short* __restrict__ wbs,
    float* __restrict__ out) {
    __shared__ unsigned short cbuf[64][136];  // 17.4 KB; rows 16B-aligned (272 B)
    __shared__ int sscol[TCAP];               // 8 KB
    __shared__ int nhist[64];
    __shared__ int nst[65];
    __shared__ int ncurs[64];

    const int t = threadIdx.x;
    const int blk = blockIdx.x;
    const int base = blk * 64;
    const int st0 = bbase[blk];
    const int en0 = bbase[blk + 1];
    const int ecount = en0 - st0;
    const bool fits = (ecount <= TCAP);  // block-uniform

    const int s = t >> 2;  // node slot 0..63
    const int g = t & 3;   // 32-byte bf16 chunk index
    const int node = base + s;

    float a[16];
#pragma unroll
    for (int j = 0; j < 16; j++) a[j] = 0.f;
    int deg = 0;

    if (fits) {
        int* tpack = (int*)&cbuf[0][0];  // 8 KB overlay, dead before cbuf writes
        for (int i = t; i < ecount; i += 256) tpack[i] = (int)tbuf[st0 + i];
        if (t < 64) nhist[t] = 0;
        __syncthreads();
        for (int i = t; i < ecount; i += 256) atomicAdd(&nhist[tpack[i] >> 17], 1);
        __syncthreads();
        if (t < 64) {  // exclusive scan of 64 counts in wave 0
            int v = nhist[t];
            int incl = v;
#pragma unroll
            for (int off = 1; off < 64; off <<= 1) {
                int u = __shfl_up(incl, off, 64);
                if (t >= off) incl += u;
            }
            nst[t + 1] = incl;
            if (t == 0) nst[0] = 0;
            ncurs[t] = incl - v;
        }
        __syncthreads();
        for (int i = t; i < ecount; i += 256) {
            int p = tpack[i];
            int lr = p >> 17;
            int pos = atomicAdd(&ncurs[lr], 1);
            sscol[pos] = p & 0x1FFFF;
        }
        __syncthreads();

        // Gather: 4 lanes/node, 32 B bf16 chunks, 4-edge unroll (8 loads in flight)
        int st = nst[s], en = nst[s + 1];
        deg = en - st;
        int p = st;
        for (; p + 4 <= en; p += 4) {
            int c0 = sscol[p], c1 = sscol[p + 1], c2 = sscol[p + 2], c3 = sscol[p + 3];
            const uint4* r0p = (const uint4*)(fb + (size_t)c0 * 64) + g * 2;
            const uint4* r1p = (const uint4*)(fb + (size_t)c1 * 64) + g * 2;
            const uint4* r2p = (const uint4*)(fb + (size_t)c2 * 64) + g * 2;
            const uint4* r3p = (const uint4*)(fb + (size_t)c3 * 64) + g * 2;
            uint4 v00 = r0p[0], v01 = r0p[1];
            uint4 v10 = r1p[0], v11 = r1p[1];
            uint4 v20 = r2p[0], v21 = r2p[1];
            uint4 v30 = r3p[0], v31 = r3p[1];
            acc8(a, v00); acc8(a + 8, v01);
            acc8(a, v10); acc8(a + 8, v11);
            acc8(a, v20); acc8(a + 8, v21);
            acc8(a, v30); acc8(a + 8, v31);
        }
        if (p + 2 <= en) {
            int c0 = sscol[p], c1 = sscol[p + 1];
            const uint4* r0p = (const uint4*)(fb + (size_t)c0 * 64) + g * 2;
            const uint4* r1p = (const uint4*)(fb + (size_t)c1 * 64) + g * 2;
            uint4 v00 = r0p[0], v01 = r0p[1];
            uint4 v10 = r1p[0], v11 = r1p[1];
            acc8(a, v00); acc8(a + 8, v01);
            acc8(a, v10); acc8(a + 8, v11);
            p += 2;
        }
        if (p < en) {
            int c0 = sscol[p];
            const uint4* r0p = (const uint4*)(fb + (size_t)c0 * 64) + g * 2;
            uint4 v00 = r0p[0], v01 = r0p[1];
            acc8(a, v00); acc8(a + 8, v01);
        }
    } else {  // >32 sigma; correctness-only scan-filter from global tbuf
        __syncthreads();
        for (int p = st0; p < en0; p++) {
            unsigned int pk = tbuf[p];
            if ((int)(pk >> 17) == s) {
                deg++;
                int c0 = (int)(pk & 0x1FFFFu);
                const uint4* r0p = (const uint4*)(fb + (size_t)c0 * 64) + g * 2;
                uint4 v00 = r0p[0], v01 = r0p[1];
                acc8(a, v00); acc8(a + 8, v01);
            }
        }
        __syncthreads();
    }

    // Write combined tile (bf16): own feats [0,64) + normalized neigh [64,128)
    {
        float rd = 1.0f / (float)(deg + 1);
#pragma unroll
        for (int q = 0; q < 4; q++) {
            ushort4 o;
            o.x = f2bf(a[q * 4 + 0] * rd);
            o.y = f2bf(a[q * 4 + 1] * rd);
            o.z = f2bf(a[q * 4 + 2] * rd);
            o.w = f2bf(a[q * 4 + 3] * rd);
            *(ushort4*)&cbuf[s][64 + g * 16 + q * 4] = o;
        }
        // own features: already bf16 in fb
        uint4 f0 = make_uint4(0, 0, 0, 0), f1 = make_uint4(0, 0, 0, 0);
        if (node < N_NODES) {
            f0 = *(const uint4*)&fb[(size_t)node * 64 + g * 16];
            f1 = *(const uint4*)&fb[(size_t)node * 64 + g * 16 + 8];
        }
        *(uint4*)&cbuf[s][g * 16] = f0;
        *(uint4*)&cbuf[s][g * 16 + 8] = f1;
    }
    __syncthreads();

    // MFMA GEMM: wave w handles rows w*16..w*16+15, all 128 cols.
    {
        const int lane = t & 63;
        const int wave = t >> 6;
        const int quad = lane >> 4;
        const int l15 = lane & 15;

        f32x4 acc[8];
#pragma unroll
        for (int nt = 0; nt < 8; nt++) acc[nt] = (f32x4){0.f, 0.f, 0.f, 0.f};

#pragma unroll
        for (int kblk = 0; kblk < 4; kblk++) {
            bf16x8 af = *(const bf16x8*)&cbuf[wave * 16 + l15][kblk * 32 + quad * 8];
            const unsigned short* wp = wbs + kblk * 512 + lane * 8;
#pragma unroll
            for (int nt = 0; nt < 8; nt++) {
                bf16x8 bf = *(const bf16x8*)(wp + nt * 2048);
                acc[nt] = __builtin_amdgcn_mfma_f32_16x16x32_bf16(af, bf, acc[nt], 0, 0, 0);
            }
        }

        // D layout: col = lane&15, row = quad*4 + reg
#pragma unroll
        for (int nt = 0; nt < 8; nt++) {
#pragma unroll
            for (int r = 0; r < 4; r++) {
                int gr = base + wave * 16 + quad * 4 + r;
                if (gr < N_NODES)
                    out[(size_t)gr * 128 + nt * 16 + l15] = fmaxf(acc[nt][r], 0.f);
            }
        }
    }
}

extern "C" void kernel_launch(void* const* d_in, const int* in_sizes, int n_in,
                              void* d_out, int out_size, void* d_ws, size_t ws_size,
                              hipStream_t stream) {
    const float* feat = (const float*)d_in[0];
    const int* row = (const int*)d_in[1];
    const int* col = (const int*)d_in[2];
    const float* W = (const float*)d_in[3];
    float* out = (float*)d_out;

    unsigned short* fb = (unsigned short*)d_ws;  // 6.4 MB
    unsigned short* wbs = fb + (size_t)N_NODES * 64;  // 16384 ushort
    int* bhist = (int*)(wbs + 16384);
    int* bbase = bhist + NBUCKET;      // NBUCKET+1
    int* bcur = bbase + NBUCKET + 1;   // NBUCKET
    unsigned int* tbuf = (unsigned int*)(bcur + NBUCKET);  // NEDGE

    hipMemsetAsync(bhist, 0, NBUCKET * sizeof(int), stream);
    conv_bhist_kernel<<<CONVB + PARTB, 512, 0, stream>>>(feat, fb, row, bhist);
    bscan_kernel<<<1, 1024, 0, stream>>>(bhist, W, bbase, bcur, wbs);
    part_kernel<<<PARTB, 512, 0, stream>>>(row, col, bcur, tbuf);
    fused_kernel<<<NBUCKET, 256, 0, stream>>>(fb, bbase, tbuf, wbs, out);
}

// Round 12
// 124.997 us; speedup vs baseline: 3.1564x; 1.0193x over previous
//
#include <hip/hip_runtime.h>

#define N_NODES 50000
#define NEDGE 800000
#define NEDGE4 (NEDGE / 4)   // 200000 int4s
#define CONVB 1563           // ceil(800000 float4 / 512)
#define PARTB 98             // ceil(200000 int4 / (512*4))
#define NBUCKET 782          // one bucket per 64-node fused tile
#define TCAP 2048            // per-tile edge cap (mean 1024, sd 32)

typedef __attribute__((ext_vector_type(8))) short bf16x8;
typedef __attribute__((ext_vector_type(4))) float f32x4;
typedef __attribute__((ext_vector_type(2))) float f32x2;

// ws layout:
//   fb8   [N_NODES*16]  uint: fp8-e4m3 features, 4/uint   3.2 MB
//   wbs   [16384]       ushort: W in MFMA B-fragment layout (32 KB)
//   bhist [NBUCKET]     int (zeroed via memset)
//   bbase [NBUCKET+1]   int
//   bcur  [NBUCKET]     int
//   tbuf  [NEDGE]       uint packed (localrow<<17)|col

__device__ __forceinline__ unsigned short f2bf(float x) {
    unsigned int u = __float_as_uint(x);
    unsigned int r = (u + 0x7FFFu + ((u >> 16) & 1u)) >> 16;  // RNE
    return (unsigned short)r;
}

// decode 16 fp8 (uint4) and accumulate into a[0..15]
__device__ __forceinline__ void acc16_fp8(float* a, uint4 v) {
    f32x2 t;
    t = __builtin_amdgcn_cvt_pk_f32_fp8(v.x, false); a[0] += t[0];  a[1] += t[1];
    t = __builtin_amdgcn_cvt_pk_f32_fp8(v.x, true);  a[2] += t[0];  a[3] += t[1];
    t = __builtin_amdgcn_cvt_pk_f32_fp8(v.y, false); a[4] += t[0];  a[5] += t[1];
    t = __builtin_amdgcn_cvt_pk_f32_fp8(v.y, true);  a[6] += t[0];  a[7] += t[1];
    t = __builtin_amdgcn_cvt_pk_f32_fp8(v.z, false); a[8] += t[0];  a[9] += t[1];
    t = __builtin_amdgcn_cvt_pk_f32_fp8(v.z, true);  a[10] += t[0]; a[11] += t[1];
    t = __builtin_amdgcn_cvt_pk_f32_fp8(v.w, false); a[12] += t[0]; a[13] += t[1];
    t = __builtin_amdgcn_cvt_pk_f32_fp8(v.w, true);  a[14] += t[0]; a[15] += t[1];
}

// K1: feat->fp8 convert (blocks < CONVB) || bucket histogram (blocks >= CONVB)
__global__ __launch_bounds__(512) void conv_bhist_kernel(
    const float* __restrict__ feat, unsigned int* __restrict__ fb8,
    const int* __restrict__ row, int* __restrict__ bhist) {
    __shared__ int hist[NBUCKET];
    const int b = blockIdx.x;
    const int t = threadIdx.x;
    if (b < CONVB) {
        int i = b * 512 + t;
        if (i < N_NODES * 16) {
            float4 v = ((const float4*)feat)[i];
            unsigned int p = 0;
            p = __builtin_amdgcn_cvt_pk_fp8_f32(v.x, v.y, p, false);
            p = __builtin_amdgcn_cvt_pk_fp8_f32(v.z, v.w, p, true);
            fb8[i] = p;
        }
    } else {
        for (int i = t; i < NBUCKET; i += 512) hist[i] = 0;
        __syncthreads();
        const int base4 = (b - CONVB) * 2048;
#pragma unroll
        for (int k = 0; k < 4; k++) {
            int i4 = base4 + k * 512 + t;
            if (i4 < NEDGE4) {
                int4 r = ((const int4*)row)[i4];
                atomicAdd(&hist[r.x >> 6], 1);
                atomicAdd(&hist[r.y >> 6], 1);
                atomicAdd(&hist[r.z >> 6], 1);
                atomicAdd(&hist[r.w >> 6], 1);
            }
        }
        __syncthreads();
        for (int i = t; i < NBUCKET; i += 512)
            if (hist[i]) atomicAdd(&bhist[i], hist[i]);
    }
}

// K2: single-block scan of 782 bucket counts + W -> B-fragment bf16 pack.
__global__ __launch_bounds__(1024) void bscan_kernel(
    const int* __restrict__ bhist, const float* __restrict__ W,
    int* __restrict__ bbase, int* __restrict__ bcur,
    unsigned short* __restrict__ wbs) {
    __shared__ int buf[1024];
    const int t = threadIdx.x;
    int v = (t < NBUCKET) ? bhist[t] : 0;
    buf[t] = v;
    __syncthreads();
    for (int off = 1; off < 1024; off <<= 1) {
        int add = (t >= off) ? buf[t - off] : 0;
        __syncthreads();
        buf[t] += add;
        __syncthreads();
    }
    int excl = buf[t] - v;
    if (t < NBUCKET) { bbase[t] = excl; bcur[t] = excl; }
    if (t == NBUCKET - 1) bbase[NBUCKET] = excl + v;

    for (int i = t; i < 16384; i += 1024) {
        int j = i & 7;
        int lane = (i >> 3) & 63;
        int kblk = (i >> 9) & 3;
        int nt = i >> 11;
        int k = kblk * 32 + (lane >> 4) * 8 + j;
        int n = nt * 16 + (lane & 15);
        wbs[i] = f2bf(W[k * 128 + n]);
    }
}

// K3: partition edges into 782 tile-buckets (packed writes into dense runs).
__global__ __launch_bounds__(512) void part_kernel(
    const int* __restrict__ row, const int* __restrict__ col,
    int* __restrict__ bcur, unsigned int* __restrict__ tbuf) {
    __shared__ int hist[NBUCKET];
    __shared__ int rbase[NBUCKET];
    __shared__ int lcur[NBUCKET];
    const int t = threadIdx.x;
    for (int i = t; i < NBUCKET; i += 512) hist[i] = 0;
    __syncthreads();

    const int base4 = blockIdx.x * 2048;  // 8192 edges per block
    int4 rv[4], cv[4];
#pragma unroll
    for (int k = 0; k < 4; k++) {
        int i4 = base4 + k * 512 + t;
        if (i4 < NEDGE4) {
            rv[k] = ((const int4*)row)[i4];
            cv[k] = ((const int4*)col)[i4];
            atomicAdd(&hist[rv[k].x >> 6], 1);
            atomicAdd(&hist[rv[k].y >> 6], 1);
            atomicAdd(&hist[rv[k].z >> 6], 1);
            atomicAdd(&hist[rv[k].w >> 6], 1);
        } else {
            rv[k] = make_int4(-1, -1, -1, -1);
            cv[k] = make_int4(0, 0, 0, 0);
        }
    }
    __syncthreads();

    for (int i = t; i < NBUCKET; i += 512) {
        rbase[i] = atomicAdd(&bcur[i], hist[i]);
        lcur[i] = 0;
    }
    __syncthreads();

#pragma unroll
    for (int k = 0; k < 4; k++) {
        if (rv[k].x < 0) continue;
        int rr[4] = {rv[k].x, rv[k].y, rv[k].z, rv[k].w};
        int cc[4] = {cv[k].x, cv[k].y, cv[k].z, cv[k].w};
#pragma unroll
        for (int j = 0; j < 4; j++) {
            int bk = rr[j] >> 6;
            int pos = rbase[bk] + atomicAdd(&lcur[bk], 1);
            tbuf[pos] = ((unsigned int)(rr[j] & 63) << 17) | (unsigned int)cc[j];
        }
    }
}

// K4: in-LDS counting-sort + fp8 gather (1 line/row) + MFMA GEMM + ReLU.
// 64 nodes / 256 threads. LDS: cbuf 17.4 KB (tpack overlays) + sscol 8 KB.
__global__ __launch_bounds__(256) void fused_kernel(
    const float* __restrict__ feat,
    const unsigned int* __restrict__ fb8,
    const int* __restrict__ bbase,
    const unsigned int* __restrict__ tbuf,
    const unsigned short* __restrict__ wbs,
    float* __restrict__ out) {
    __shared__ unsigned short cbuf[64][136];  // rows 16B-aligned (272 B)
    __shared__ int sscol[TCAP];               // 8 KB
    __shared__ int nhist[64];
    __shared__ int nst[65];
    __shared__ int ncurs[64];

    const int t = threadIdx.x;
    const int blk = blockIdx.x;
    const int base = blk * 64;
    const int st0 = bbase[blk];
    const int en0 = bbase[blk + 1];
    const int ecount = en0 - st0;
    const bool fits = (ecount <= TCAP);  // block-uniform

    const int s = t >> 2;  // node slot 0..63
    const int g = t & 3;   // 16-byte fp8 chunk index (16 feats)
    const int node = base + s;

    float a[16];
#pragma unroll
    for (int j = 0; j < 16; j++) a[j] = 0.f;
    int deg = 0;

    if (fits) {
        int* tpack = (int*)&cbuf[0][0];  // 8 KB overlay, dead before cbuf writes
        for (int i = t; i < ecount; i += 256) tpack[i] = (int)tbuf[st0 + i];
        if (t < 64) nhist[t] = 0;
        __syncthreads();
        for (int i = t; i < ecount; i += 256) atomicAdd(&nhist[tpack[i] >> 17], 1);
        __syncthreads();
        if (t < 64) {  // exclusive scan of 64 counts in wave 0
            int v = nhist[t];
            int incl = v;
#pragma unroll
            for (int off = 1; off < 64; off <<= 1) {
                int u = __shfl_up(incl, off, 64);
                if (t >= off) incl += u;
            }
            nst[t + 1] = incl;
            if (t == 0) nst[0] = 0;
            ncurs[t] = incl - v;
        }
        __syncthreads();
        for (int i = t; i < ecount; i += 256) {
            int p = tpack[i];
            int lr = p >> 17;
            int pos = atomicAdd(&ncurs[lr], 1);
            sscol[pos] = p & 0x1FFFF;
        }
        __syncthreads();

        // Gather: 4 lanes/node, 16 B fp8 chunks (row = 64 B = 1 line),
        // 4-edge unroll (4 loads in flight per lane)
        int st = nst[s], en = nst[s + 1];
        deg = en - st;
        int p = st;
        for (; p + 4 <= en; p += 4) {
            int c0 = sscol[p], c1 = sscol[p + 1], c2 = sscol[p + 2], c3 = sscol[p + 3];
            uint4 v0 = ((const uint4*)(fb8 + (size_t)c0 * 16))[g];
            uint4 v1 = ((const uint4*)(fb8 + (size_t)c1 * 16))[g];
            uint4 v2 = ((const uint4*)(fb8 + (size_t)c2 * 16))[g];
            uint4 v3 = ((const uint4*)(fb8 + (size_t)c3 * 16))[g];
            acc16_fp8(a, v0); acc16_fp8(a, v1);
            acc16_fp8(a, v2); acc16_fp8(a, v3);
        }
        for (; p < en; p++) {
            int c0 = sscol[p];
            uint4 v0 = ((const uint4*)(fb8 + (size_t)c0 * 16))[g];
            acc16_fp8(a, v0);
        }
    } else {  // >32 sigma; correctness-only scan-filter from global tbuf
        __syncthreads();
        for (int p = st0; p < en0; p++) {
            unsigned int pk = tbuf[p];
            if ((int)(pk >> 17) == s) {
                deg++;
                int c0 = (int)(pk & 0x1FFFFu);
                uint4 v0 = ((const uint4*)(fb8 + (size_t)c0 * 16))[g];
                acc16_fp8(a, v0);
            }
        }
        __syncthreads();
    }

    // Write combined tile (bf16): own fp32 feats [0,64) + normalized neigh [64,128)
    {
        float rd = 1.0f / (float)(deg + 1);
#pragma unroll
        for (int q = 0; q < 4; q++) {
            ushort4 o;
            o.x = f2bf(a[q * 4 + 0] * rd);
            o.y = f2bf(a[q * 4 + 1] * rd);
            o.z = f2bf(a[q * 4 + 2] * rd);
            o.w = f2bf(a[q * 4 + 3] * rd);
            *(ushort4*)&cbuf[s][64 + g * 16 + q * 4] = o;
        }
        // own features: exact fp32 -> bf16
#pragma unroll
        for (int q = 0; q < 4; q++) {
            float4 f = make_float4(0.f, 0.f, 0.f, 0.f);
            if (node < N_NODES) f = *(const float4*)&feat[(size_t)node * 64 + g * 16 + q * 4];
            ushort4 o;
            o.x = f2bf(f.x); o.y = f2bf(f.y); o.z = f2bf(f.z); o.w = f2bf(f.w);
            *(ushort4*)&cbuf[s][g * 16 + q * 4] = o;
        }
    }
    __syncthreads();

    // MFMA GEMM: wave w handles rows w*16..w*16+15, all 128 cols.
    {
        const int lane = t & 63;
        const int wave = t >> 6;
        const int quad = lane >> 4;
        const int l15 = lane & 15;

        f32x4 acc[8];
#pragma unroll
        for (int nt = 0; nt < 8; nt++) acc[nt] = (f32x4){0.f, 0.f, 0.f, 0.f};

#pragma unroll
        for (int kblk = 0; kblk < 4; kblk++) {
            bf16x8 af = *(const bf16x8*)&cbuf[wave * 16 + l15][kblk * 32 + quad * 8];
            const unsigned short* wp = wbs + kblk * 512 + lane * 8;
#pragma unroll
            for (int nt = 0; nt < 8; nt++) {
                bf16x8 bf = *(const bf16x8*)(wp + nt * 2048);
                acc[nt] = __builtin_amdgcn_mfma_f32_16x16x32_bf16(af, bf, acc[nt], 0, 0, 0);
            }
        }

        // D layout: col = lane&15, row = quad*4 + reg
#pragma unroll
        for (int nt = 0; nt < 8; nt++) {
#pragma unroll
            for (int r = 0; r < 4; r++) {
                int gr = base + wave * 16 + quad * 4 + r;
                if (gr < N_NODES)
                    out[(size_t)gr * 128 + nt * 16 + l15] = fmaxf(acc[nt][r], 0.f);
            }
        }
    }
}

extern "C" void kernel_launch(void* const* d_in, const int* in_sizes, int n_in,
                              void* d_out, int out_size, void* d_ws, size_t ws_size,
                              hipStream_t stream) {
    const float* feat = (const float*)d_in[0];
    const int* row = (const int*)d_in[1];
    const int* col = (const int*)d_in[2];
    const float* W = (const float*)d_in[3];
    float* out = (float*)d_out;

    unsigned int* fb8 = (unsigned int*)d_ws;              // N_NODES*16 uints, 3.2 MB
    unsigned short* wbs = (unsigned short*)(fb8 + (size_t)N_NODES * 16);  // 16384
    int* bhist = (int*)(wbs + 16384);
    int* bbase = bhist + NBUCKET;      // NBUCKET+1
    int* bcur = bbase + NBUCKET + 1;   // NBUCKET
    unsigned int* tbuf = (unsigned int*)(bcur + NBUCKET);  // NEDGE

    hipMemsetAsync(bhist, 0, NBUCKET * sizeof(int), stream);
    conv_bhist_kernel<<<CONVB + PARTB, 512, 0, stream>>>(feat, fb8, row, bhist);
    bscan_kernel<<<1, 1024, 0, stream>>>(bhist, W, bbase, bcur, wbs);
    part_kernel<<<PARTB, 512, 0, stream>>>(row, col, bcur, tbuf);
    fused_kernel<<<NBUCKET, 256, 0, stream>>>(feat, fb8, bbase, tbuf, wbs, out);
}